// Round 14
// baseline (915.912 us; speedup 1.0000x reference)
//
#include <hip/hip_runtime.h>

typedef unsigned short u16;
typedef __attribute__((ext_vector_type(8))) short bf16x8;
typedef __attribute__((ext_vector_type(4))) float f32x4;
typedef __attribute__((ext_vector_type(8))) unsigned short u16x8;
typedef __attribute__((ext_vector_type(4))) unsigned short u16x4;

__device__ __forceinline__ u16 f2bf(float f){
  unsigned int u = __builtin_bit_cast(unsigned int, f);
  u += 0x7FFFu + ((u >> 16) & 1u);
  return (u16)(u >> 16);
}
__device__ __forceinline__ float bf2f(u16 h){
  unsigned int u = ((unsigned int)h) << 16;
  return __builtin_bit_cast(float, u);
}
__device__ __forceinline__ u16x8 cvt8(float4 a, float4 b){
  u16x8 o = { f2bf(a.x), f2bf(a.y), f2bf(a.z), f2bf(a.w),
              f2bf(b.x), f2bf(b.y), f2bf(b.z), f2bf(b.w) };
  return o;
}

__device__ __forceinline__ void load16(const u16* g, u16* s){
  __builtin_amdgcn_global_load_lds((const __attribute__((address_space(1))) unsigned int*)g,
                                   (__attribute__((address_space(3))) unsigned int*)s,
                                   16, 0, 0);
}

// From R: S = 0.5(A-A^T). Sbf = bf16(S); Dbf = bf16((c+1)(cI - S)), c=1.000001
__global__ __launch_bounds__(256) void build_s(const float* __restrict__ R, u16* __restrict__ Sbf,
                                               u16* __restrict__ Dbf){
  int idx = blockIdx.x * 256 + threadIdx.x;
  int b = idx >> 18;
  int i = (idx >> 9) & 511;
  int j = idx & 511;
  float a  = R[idx];
  float at = R[(b << 18) + (j << 9) + i];
  float s = 0.5f * (a - at);
  Sbf[idx] = f2bf(s);
  Dbf[idx] = f2bf((i == j ? 2.000003f : 0.0f) - 2.000001f * s);
}

// Wt[b][i][j] = W[b*512 + j][i]  (bf16), i in [0,4096), j in [0,512)
__global__ __launch_bounds__(256) void transpose_w(const float* __restrict__ W, u16* __restrict__ Wt){
  const int b = blockIdx.z;
  const int i0 = blockIdx.x << 5;
  const int j0 = blockIdx.y << 5;
  __shared__ float tile[32][33];
  const int t = threadIdx.x;
  const int r = t >> 3, c = (t & 7) << 2;
  float4 v = *(const float4*)&W[(size_t)((b << 9) + j0 + r) * 4096 + i0 + c];
  tile[r][c+0] = v.x; tile[r][c+1] = v.y; tile[r][c+2] = v.z; tile[r][c+3] = v.w;
  __syncthreads();
  u16x4 o = { f2bf(tile[c+0][r]), f2bf(tile[c+1][r]), f2bf(tile[c+2][r]), f2bf(tile[c+3][r]) };
  *(u16x4*)&Wt[((size_t)b << 21) + (size_t)(i0 + r) * 512 + j0 + c] = o;
}

// 64x64-tile bt-form bf16 MFMA gemm for the small NS steps: grid (N/64, M/64, 8)
// = 512 blocks (2 blocks/CU). 4 waves (2Mx2N), each 32x32 (2x2 16x16x32 frags).
// Single-buffered LDS, __syncthreads staging (deterministic class), 4-slot XOR
// swizzle: LDS[r][slot] = G[r][slot ^ (r&3)], read slot ((l>>4)^l)&3.
// EPI 2:  bf16 C = acc
// EPI 3:  bf16 C = 2*diag - acc
// EPI 9:  bf16 C = acc - diag
// EPI 11: p = acc + c^2*diag (f32): Cout(width1024)=[bf16(p)|bf16(p-ph)];
//         x1 = bf16(2b*diag - b^2*p) -> aux (width 512) and aux2 (width 1024, dup)
template<int EPI>
__global__ __launch_bounds__(256) void gemm_ns(const u16* __restrict__ A, const u16* __restrict__ B,
                                               void* __restrict__ Cout, void* __restrict__ aux,
                                               void* __restrict__ aux2,
                                               int M, int N, int K){
  const int bz = blockIdx.z;
  const char* Ab = (const char*)(A + (size_t)bz * M * K);
  const char* Bb = (const char*)(B + (size_t)bz * N * K);
  const int m0 = blockIdx.y << 6, n0 = blockIdx.x << 6;
  __shared__ __align__(16) char As[4096];
  __shared__ __align__(16) char Bs[4096];
  const int t = threadIdx.x;
  const int w = t >> 6, l = t & 63;
  const int wm = w >> 1, wn = w & 1;
  const size_t Kb = (size_t)K << 1;
  const int sR = t >> 2;
  const int sK = ((t ^ (t >> 2)) & 3) << 4;
  const int kq = (((l >> 4) ^ l) & 3) << 4;
  const int aRd = ((wm << 5) + (l & 15)) * 64 + kq;
  const int bRd = ((wn << 5) + (l & 15)) * 64 + kq;
  f32x4 acc[2][2] = {};
  for (int k0 = 0; k0 < K; k0 += 32){
    const size_t kb = (size_t)k0 << 1;
    load16((const u16*)(Ab + (size_t)(m0 + sR) * Kb + kb + sK), (u16*)(As + t * 16));
    load16((const u16*)(Bb + (size_t)(n0 + sR) * Kb + kb + sK), (u16*)(Bs + t * 16));
    __syncthreads();
    bf16x8 aF[2], bF[2];
#pragma unroll
    for (int mf = 0; mf < 2; ++mf) aF[mf] = *(const bf16x8*)(As + aRd + (mf << 10));
#pragma unroll
    for (int nf = 0; nf < 2; ++nf) bF[nf] = *(const bf16x8*)(Bs + bRd + (nf << 10));
#pragma unroll
    for (int mf = 0; mf < 2; ++mf)
#pragma unroll
      for (int nf = 0; nf < 2; ++nf)
        acc[mf][nf] = __builtin_amdgcn_mfma_f32_16x16x32_bf16(aF[mf], bF[nf], acc[mf][nf], 0, 0, 0);
    __syncthreads();
  }
#pragma unroll
  for (int mf = 0; mf < 2; ++mf){
#pragma unroll
    for (int nf = 0; nf < 2; ++nf){
      const int col = n0 + (wn << 5) + (nf << 4) + (l & 15);
#pragma unroll
      for (int q = 0; q < 4; ++q){
        const int row = m0 + (wm << 5) + (mf << 4) + ((l >> 4) << 2) + q;
        float v = acc[mf][nf][q];
        size_t gi = ((size_t)bz * M + row) * N + col;
        size_t g2 = (((size_t)bz * M + row) << 10) + col;
        if (EPI == 2){
          ((u16*)Cout)[gi] = f2bf(v);
        } else if (EPI == 3){
          ((u16*)Cout)[gi] = f2bf((row == col ? 2.0f : 0.0f) - v);
        } else if (EPI == 9){
          ((u16*)Cout)[gi] = f2bf(v - (row == col ? 1.0f : 0.0f));
        } else {  // EPI 11
          float p = v + (row == col ? 1.000002f : 0.0f);
          u16 ph = f2bf(p);
          ((u16*)Cout)[g2] = ph;
          ((u16*)Cout)[g2 + 512] = f2bf(p - bf2f(ph));
          const float beta = 0.8264463f;
          u16 x1 = f2bf((row == col ? 2.0f * beta : 0.0f) - beta * beta * p);
          ((u16*)aux)[gi] = x1;
          ((u16*)aux2)[g2] = x1;
          ((u16*)aux2)[g2 + 512] = x1;
        }
      }
    }
  }
}

// 256x256-tile bt-form bf16 MFMA gemm — ROUND-9 VERSION VERBATIM (replay-stable).
// Used only for the filt GEMM (EPI 2).
template<int EPI>
__global__ __launch_bounds__(512, 2) void gemm256(const u16* __restrict__ A, const u16* __restrict__ B,
                                                  void* __restrict__ Cout, const float* __restrict__ aux,
                                                  int M, int N, int K){
  __shared__ __align__(16) char lds[131072];
  const int bz = blockIdx.z;
  const char* Ab = (const char*)(A + (size_t)bz * M * K);
  const char* Bb = (const char*)(B + (size_t)bz * N * K);
  const int NB = N >> 8;
  const int nwg = gridDim.x;
  const int bid = blockIdx.x;
  const int swzb = (bid & 7) * (nwg >> 3) + (bid >> 3);   // nwg % 8 == 0
  const int m0 = (swzb / NB) << 8;
  const int n0 = (swzb % NB) << 8;
  const int tid = threadIdx.x;
  const int w = tid >> 6, l = tid & 63;
  const int wm = w >> 2, wn = w & 3;
  const size_t Kb = (size_t)K << 1;
  const int NT = K >> 6;
  const int sRow = tid >> 3;
  const int sCol = ((tid & 7) << 4) ^ ((sRow & 7) << 4);
  const int sDst = tid << 4;
  const char* aS = Ab + (size_t)(m0 + sRow) * Kb + sCol;
  const char* bS = Bb + (size_t)(n0 + sRow) * Kb + sCol;
  const int lrow = (l & 15) << 7;
  const int kq0 = (((l >> 4) << 4)) ^ ((l & 7) << 4);
  const int aOff = (wm << 14) + lrow;
  const int bOff = 32768 + ((wn >> 1) << 14) + ((wn & 1) << 13) + lrow;

#define STAGE_H(isB, h, tt) { \
    const int _lo = (((tt) & 1) << 16) + ((isB) << 15) + ((h) << 14); \
    const char* _s = ((isB) ? bS : aS) + ((size_t)((h) << 7)) * Kb + ((size_t)(tt) << 7); \
    load16((const u16*)_s, (u16*)(lds + _lo + sDst)); \
    load16((const u16*)(_s + (Kb << 6)), (u16*)(lds + _lo + 8192 + sDst)); }

#define RD_A(bufb, UQ) \
  _Pragma("unroll") for (int i2 = 0; i2 < 4; ++i2){ \
    aF[i2][0] = *(const bf16x8*)(lds + (bufb) + aOff + ((UQ) << 13) + (i2 << 11) + kq0); \
    aF[i2][1] = *(const bf16x8*)(lds + (bufb) + aOff + ((UQ) << 13) + (i2 << 11) + (kq0 ^ 64)); }

#define RD_B(bufb, VQ) \
  _Pragma("unroll") for (int j2 = 0; j2 < 2; ++j2){ \
    bF[VQ][j2][0] = *(const bf16x8*)(lds + (bufb) + bOff + ((VQ) << 12) + (j2 << 11) + kq0); \
    bF[VQ][j2][1] = *(const bf16x8*)(lds + (bufb) + bOff + ((VQ) << 12) + (j2 << 11) + (kq0 ^ 64)); }

#define MFMA16(UQ, VQ) \
    _Pragma("unroll") for (int i2 = 0; i2 < 4; ++i2) \
      _Pragma("unroll") for (int j2 = 0; j2 < 2; ++j2){ \
        acc[(UQ)*4+i2][(VQ)*2+j2] = __builtin_amdgcn_mfma_f32_16x16x32_bf16(aF[i2][0], bF[VQ][j2][0], acc[(UQ)*4+i2][(VQ)*2+j2], 0, 0, 0); \
        acc[(UQ)*4+i2][(VQ)*2+j2] = __builtin_amdgcn_mfma_f32_16x16x32_bf16(aF[i2][1], bF[VQ][j2][1], acc[(UQ)*4+i2][(VQ)*2+j2], 0, 0, 0); }

#define BAR asm volatile("s_barrier" ::: "memory");
#define VM0 asm volatile("s_waitcnt vmcnt(0)" ::: "memory");

  bf16x8 aF[4][2], bF[2][2][2];
  f32x4 acc[8][4] = {};

  STAGE_H(0,0,0) STAGE_H(1,0,0) STAGE_H(0,1,0) STAGE_H(1,1,0)
  VM0 BAR

#define KTILE(t, bufb) { \
    RD_A(bufb, 0) RD_B(bufb, 0) \
    if ((t) + 1 < NT) { STAGE_H(0,0,(t)+1) STAGE_H(1,0,(t)+1) } \
    MFMA16(0,0) \
    RD_B(bufb, 1) \
    if ((t) + 1 < NT) { STAGE_H(0,1,(t)+1) STAGE_H(1,1,(t)+1) } \
    MFMA16(0,1) \
    RD_A(bufb, 1) \
    MFMA16(1,1) \
    MFMA16(1,0) \
    __builtin_amdgcn_sched_barrier(0); \
    VM0 BAR }

#pragma unroll 1
  for (int tp = 0; tp < NT; tp += 2){
    KTILE(tp, 0)
    KTILE(tp+1, 65536)
  }
#undef KTILE

#pragma unroll
  for (int mf = 0; mf < 8; ++mf){
#pragma unroll
    for (int nf = 0; nf < 4; ++nf){
      const int col = n0 + (wn << 6) + (nf << 4) + (l & 15);
#pragma unroll
      for (int q = 0; q < 4; ++q){
        const int row = m0 + (wm << 7) + (mf << 4) + ((l >> 4) << 2) + q;
        float v = acc[mf][nf][q];
        if (EPI == 0){
          ((float*)Cout)[(size_t)row * N + col] = v + aux[col];
        } else {
          ((u16*)Cout)[((size_t)bz * M + row) * N + col] = f2bf(v);
        }
      }
    }
  }
#undef STAGE_H
#undef RD_A
#undef RD_B
#undef MFMA16
#undef BAR
#undef VM0
}

// gemm256f v2: fused f32-x A-operand with a TWO-TILE-DEEP register pipeline.
// A data for tile u: ISSUED in tile u-2 (8x float4 -> set S[u&1]), cvt+ds_write
// at END of tile u-1 into buf[u&1] (the non-read buffer). Issue->write distance
// ~1.8 tiles ~ 1100 cyc > 900-cyc HBM latency (round-13's 310-cyc gap was the
// 34%-util regression). The asm barriers pin issues in their tile (no sinking).
// B path: proven global_load_lds. Tile end: sched_barrier + lgkmcnt(0)
// [ds_writes drained] + vmcnt(0) [B stages drained; A-issues are older] + BAR.
// Same race-free class as round 9. f32 out = acc + bias[col].
__global__ __launch_bounds__(512, 2) void gemm256f(const float* __restrict__ Af, const u16* __restrict__ Bw,
                                                   float* __restrict__ Cout, const float* __restrict__ bias,
                                                   int M, int N, int K){
  __shared__ __align__(16) char lds[131072];
  const char* Bb = (const char*)Bw;
  const int NB = N >> 8;
  const int nwg = gridDim.x;
  const int bid = blockIdx.x;
  const int swzb = (bid & 7) * (nwg >> 3) + (bid >> 3);   // nwg % 8 == 0
  const int m0 = (swzb / NB) << 8;
  const int n0 = (swzb % NB) << 8;
  const int tid = threadIdx.x;
  const int w = tid >> 6, l = tid & 63;
  const int wm = w >> 2, wn = w & 3;
  const size_t Kb = (size_t)K << 1;
  const int NT = K >> 6;
  const int sRow = tid >> 3;
  const int sCol = ((tid & 7) << 4) ^ ((sRow & 7) << 4);   // bf16-byte col (swizzled)
  const int sDst = tid << 4;
  const char* bS = Bb + (size_t)(n0 + sRow) * Kb + sCol;
  const float* aS = Af + (size_t)(m0 + sRow) * K + (sCol >> 1);  // f32-elem col
  const size_t rowK64 = (size_t)64 * K;
  const int lrow = (l & 15) << 7;
  const int kq0 = (((l >> 4) << 4)) ^ ((l & 7) << 4);
  const int aOff = (wm << 14) + lrow;
  const int bOff = 32768 + ((wn >> 1) << 14) + ((wn & 1) << 13) + lrow;

#define STAGE_B(h, tt) { \
    const int _lo = (((tt) & 1) << 16) + 32768 + ((h) << 14); \
    const char* _s = bS + ((size_t)((h) << 7)) * Kb + ((size_t)(tt) << 7); \
    load16((const u16*)_s, (u16*)(lds + _lo + sDst)); \
    load16((const u16*)(_s + (Kb << 6)), (u16*)(lds + _lo + 8192 + sDst)); }

  // issue the FULL A tile tt into named set S (8x float4; chunks h=0..3 at rows h*64+sRow)
#define A_ISSUE(S, tt) if ((tt) < NT) { \
    const float* _a = aS + (size_t)(tt) * 64; \
    S##0 = *(const float4*)(_a);               S##1 = *(const float4*)(_a + 4); \
    S##2 = *(const float4*)(_a + rowK64);      S##3 = *(const float4*)(_a + rowK64 + 4); \
    S##4 = *(const float4*)(_a + 2*rowK64);    S##5 = *(const float4*)(_a + 2*rowK64 + 4); \
    S##6 = *(const float4*)(_a + 3*rowK64);    S##7 = *(const float4*)(_a + 3*rowK64 + 4); }

  // cvt + write the full A tile tt (from set S) into buf[(tt)&1]
#define A_WRITE(S, tt) if ((tt) < NT) { \
    const int _lo = (((tt) & 1) << 16); \
    *(u16x8*)(lds + _lo +         sDst) = cvt8(S##0, S##1); \
    *(u16x8*)(lds + _lo +  8192 + sDst) = cvt8(S##2, S##3); \
    *(u16x8*)(lds + _lo + 16384 + sDst) = cvt8(S##4, S##5); \
    *(u16x8*)(lds + _lo + 24576 + sDst) = cvt8(S##6, S##7); }

#define RD_A(bufb, UQ) \
  _Pragma("unroll") for (int i2 = 0; i2 < 4; ++i2){ \
    aF[i2][0] = *(const bf16x8*)(lds + (bufb) + aOff + ((UQ) << 13) + (i2 << 11) + kq0); \
    aF[i2][1] = *(const bf16x8*)(lds + (bufb) + aOff + ((UQ) << 13) + (i2 << 11) + (kq0 ^ 64)); }

#define RD_B(bufb, VQ) \
  _Pragma("unroll") for (int j2 = 0; j2 < 2; ++j2){ \
    bF[VQ][j2][0] = *(const bf16x8*)(lds + (bufb) + bOff + ((VQ) << 12) + (j2 << 11) + kq0); \
    bF[VQ][j2][1] = *(const bf16x8*)(lds + (bufb) + bOff + ((VQ) << 12) + (j2 << 11) + (kq0 ^ 64)); }

#define MFMA16(UQ, VQ) \
    _Pragma("unroll") for (int i2 = 0; i2 < 4; ++i2) \
      _Pragma("unroll") for (int j2 = 0; j2 < 2; ++j2){ \
        acc[(UQ)*4+i2][(VQ)*2+j2] = __builtin_amdgcn_mfma_f32_16x16x32_bf16(aF[i2][0], bF[VQ][j2][0], acc[(UQ)*4+i2][(VQ)*2+j2], 0, 0, 0); \
        acc[(UQ)*4+i2][(VQ)*2+j2] = __builtin_amdgcn_mfma_f32_16x16x32_bf16(aF[i2][1], bF[VQ][j2][1], acc[(UQ)*4+i2][(VQ)*2+j2], 0, 0, 0); }

#define BAR asm volatile("s_barrier" ::: "memory");
#define LGK0 asm volatile("s_waitcnt lgkmcnt(0)" ::: "memory");
#define VM0 asm volatile("s_waitcnt vmcnt(0)" ::: "memory");

  bf16x8 aF[4][2], bF[2][2][2];
  float4 p0, p1, p2, p3, p4, p5, p6, p7;   // set S0: A data for even tiles
  float4 q0, q1, q2, q3, q4, q5, q6, q7;   // set S1: A data for odd tiles
  f32x4 acc[8][4] = {};

  // prologue: issue A(0)->p, A(1)->q; stage B(0); write A(0) (one exposed wait)
  A_ISSUE(p, 0) A_ISSUE(q, 1)
  STAGE_B(0, 0) STAGE_B(1, 0)
  A_WRITE(p, 0)
  LGK0 VM0 BAR

  // KTILE(t): issue A(t+2) into Siss=S[t&1]; write A(t+1) from Swr=S[(t+1)&1]
#define KTILE(t, bufb, Siss, Swr) { \
    A_ISSUE(Siss, (t)+2) \
    RD_A(bufb, 0) RD_B(bufb, 0) \
    if ((t) + 1 < NT) { STAGE_B(0, (t)+1) } \
    MFMA16(0,0) \
    RD_B(bufb, 1) \
    if ((t) + 1 < NT) { STAGE_B(1, (t)+1) } \
    MFMA16(0,1) \
    RD_A(bufb, 1) \
    MFMA16(1,1) \
    MFMA16(1,0) \
    A_WRITE(Swr, (t)+1) \
    __builtin_amdgcn_sched_barrier(0); \
    LGK0 VM0 BAR }

#pragma unroll 1
  for (int tp = 0; tp < NT; tp += 2){
    KTILE(tp, 0, p, q)
    KTILE(tp+1, 65536, q, p)
  }
#undef KTILE

#pragma unroll
  for (int mf = 0; mf < 8; ++mf){
#pragma unroll
    for (int nf = 0; nf < 4; ++nf){
      const int col = n0 + (wn << 6) + (nf << 4) + (l & 15);
#pragma unroll
      for (int q = 0; q < 4; ++q){
        const int row = m0 + (wm << 7) + (mf << 4) + ((l >> 4) << 2) + q;
        Cout[(size_t)row * N + col] = acc[mf][nf][q] + bias[col];
      }
    }
  }
#undef STAGE_B
#undef A_ISSUE
#undef A_WRITE
#undef RD_A
#undef RD_B
#undef MFMA16
#undef BAR
#undef LGK0
#undef VM0
}

extern "C" void kernel_launch(void* const* d_in, const int* in_sizes, int n_in,
                              void* d_out, int out_size, void* d_ws, size_t ws_size,
                              hipStream_t stream){
  const float* W    = (const float*)d_in[0];
  const float* bias = (const float*)d_in[1];
  const float* x    = (const float*)d_in[2];
  const float* R    = (const float*)d_in[3];
  (void)in_sizes; (void)n_in; (void)out_size; (void)ws_size;

  char* ws = (char*)d_ws;
  const size_t MiB = (size_t)1 << 20;
  u16*   Sbf  = (u16*)(ws + 0 * MiB);    // 4 MiB ; reused as G
  u16*   Dbf  = (u16*)(ws + 4 * MiB);    // 4 MiB
  u16*   X1   = (u16*)(ws + 16 * MiB);   // 4 MiB
  u16*   Ybf  = (u16*)(ws + 20 * MiB);   // 4 MiB
  u16*   X2   = (u16*)(ws + 24 * MiB);   // 4 MiB
  u16*   Phl  = (u16*)(ws + 28 * MiB);   // 8 MiB  [Ph | Pl] width-1024
  u16*   X1d  = (u16*)(ws + 44 * MiB);   // 8 MiB  [X1 | X1] width-1024
  u16*   G    = Sbf;
  u16*   Wt   = (u16*)(ws + 8 * MiB);    // 32 MiB [8,40)
  u16*   filt = (u16*)(ws + 64 * MiB);   // 32 MiB [64,96)

  const dim3 gNS(8, 8, 8);   // 512 blocks: 64x64 tiles, 2 blocks/CU (gemm_ns)

  // Phase 1: S (bf16) and D = (c+1)(cI - S)
  build_s<<<8192, 256, 0, stream>>>(R, Sbf, Dbf);
  // Phase 2: P = c^2 I + S S^T ; fused epilogue emits Phl=[Ph|Pl], X1, X1d
  gemm_ns<11><<<gNS, 256, 0, stream>>>(Sbf, Sbf, Phl, X1, X1d, 512, 512, 512);
  // Phase 3: Y = 2I - (Ph+Pl) X1   (one K=1024 gemm, full-precision P)
  gemm_ns<3><<<gNS, 256, 0, stream>>>(Phl, X1d, Ybf, nullptr, nullptr, 512, 512, 1024);
  // Phase 4: X2 = X1 Y
  gemm_ns<2><<<gNS, 256, 0, stream>>>(X1, Ybf, X2, nullptr, nullptr, 512, 512, 512);
  // Phase 5: G = Q = D X2 - I
  gemm_ns<9><<<gNS, 256, 0, stream>>>(Dbf, X2, G, nullptr, nullptr, 512, 512, 512);
  // Phase 6: filt = G @ Wb (bf16)
  transpose_w<<<dim3(128, 16, 8), 256, 0, stream>>>(W, Wt);
  gemm256<2><<<dim3(32, 1, 8), 512, 0, stream>>>(G, Wt, (void*)filt, nullptr, 512, 4096, 512);
  // Phase 7: out = x @ filt^T + bias  (A read directly from f32 x; conv fused,
  //          2-tile-deep A register pipeline)
  gemm256f<<<dim3(512, 1, 1), 512, 0, stream>>>(x, filt, (float*)d_out, bias, 8192, 4096, 4096);
}

// Round 15
// 347.116 us; speedup vs baseline: 2.6386x; 2.6386x over previous
//
#include <hip/hip_runtime.h>

typedef unsigned short u16;
typedef __attribute__((ext_vector_type(8))) short bf16x8;
typedef __attribute__((ext_vector_type(4))) float f32x4;
typedef __attribute__((ext_vector_type(8))) unsigned short u16x8;
typedef __attribute__((ext_vector_type(4))) unsigned short u16x4;

__device__ __forceinline__ u16 f2bf(float f){
  unsigned int u = __builtin_bit_cast(unsigned int, f);
  u += 0x7FFFu + ((u >> 16) & 1u);
  return (u16)(u >> 16);
}
__device__ __forceinline__ float bf2f(u16 h){
  unsigned int u = ((unsigned int)h) << 16;
  return __builtin_bit_cast(float, u);
}

__device__ __forceinline__ void load16(const u16* g, u16* s){
  __builtin_amdgcn_global_load_lds((const __attribute__((address_space(1))) unsigned int*)g,
                                   (__attribute__((address_space(3))) unsigned int*)s,
                                   16, 0, 0);
}

// From R: S = 0.5(A-A^T). Sbf = bf16(S); Dbf = bf16((c+1)(cI - S)), c=1.000001
__global__ __launch_bounds__(256) void build_s(const float* __restrict__ R, u16* __restrict__ Sbf,
                                               u16* __restrict__ Dbf){
  int idx = blockIdx.x * 256 + threadIdx.x;
  int b = idx >> 18;
  int i = (idx >> 9) & 511;
  int j = idx & 511;
  float a  = R[idx];
  float at = R[(b << 18) + (j << 9) + i];
  float s = 0.5f * (a - at);
  Sbf[idx] = f2bf(s);
  Dbf[idx] = f2bf((i == j ? 2.000003f : 0.0f) - 2.000001f * s);
}

// vectorized f32 -> bf16 (8 elems / thread, exact multiple)
__global__ __launch_bounds__(256) void conv_bf16(const float* __restrict__ src, u16* __restrict__ dst){
  size_t i = (size_t)blockIdx.x * 256 + threadIdx.x;
  const float4* s = (const float4*)src + i * 2;
  float4 v0 = s[0], v1 = s[1];
  u16x8 o = { f2bf(v0.x), f2bf(v0.y), f2bf(v0.z), f2bf(v0.w),
              f2bf(v1.x), f2bf(v1.y), f2bf(v1.z), f2bf(v1.w) };
  *(u16x8*)(dst + i * 8) = o;
}

// Wt[b][i][j] = W[b*512 + j][i]  (bf16), i in [0,4096), j in [0,512)
__global__ __launch_bounds__(256) void transpose_w(const float* __restrict__ W, u16* __restrict__ Wt){
  const int b = blockIdx.z;
  const int i0 = blockIdx.x << 5;
  const int j0 = blockIdx.y << 5;
  __shared__ float tile[32][33];
  const int t = threadIdx.x;
  const int r = t >> 3, c = (t & 7) << 2;
  float4 v = *(const float4*)&W[(size_t)((b << 9) + j0 + r) * 4096 + i0 + c];
  tile[r][c+0] = v.x; tile[r][c+1] = v.y; tile[r][c+2] = v.z; tile[r][c+3] = v.w;
  __syncthreads();
  u16x4 o = { f2bf(tile[c+0][r]), f2bf(tile[c+1][r]), f2bf(tile[c+2][r]), f2bf(tile[c+3][r]) };
  *(u16x4*)&Wt[((size_t)b << 21) + (size_t)(i0 + r) * 512 + j0 + c] = o;
}

// 64x64-tile bt-form bf16 MFMA gemm for the small NS steps: grid (N/64, M/64, 8)
// = 512 blocks (2 blocks/CU). 4 waves (2Mx2N), each 32x32 (2x2 16x16x32 frags).
// Single-buffered LDS, __syncthreads staging (deterministic class), 4-slot XOR
// swizzle: LDS[r][slot] = G[r][slot ^ (r&3)], read slot ((l>>4)^l)&3.
// EPI 2:  bf16 C = acc
// EPI 3:  bf16 C = 2*diag - acc
// EPI 9:  bf16 C = acc - diag
// EPI 11: p = acc + c^2*diag (f32): Cout(width1024)=[bf16(p)|bf16(p-ph)];
//         x1 = bf16(2b*diag - b^2*p) -> aux (width 512) and aux2 (width 1024, dup)
template<int EPI>
__global__ __launch_bounds__(256) void gemm_ns(const u16* __restrict__ A, const u16* __restrict__ B,
                                               void* __restrict__ Cout, void* __restrict__ aux,
                                               void* __restrict__ aux2,
                                               int M, int N, int K){
  const int bz = blockIdx.z;
  const char* Ab = (const char*)(A + (size_t)bz * M * K);
  const char* Bb = (const char*)(B + (size_t)bz * N * K);
  const int m0 = blockIdx.y << 6, n0 = blockIdx.x << 6;
  __shared__ __align__(16) char As[4096];
  __shared__ __align__(16) char Bs[4096];
  const int t = threadIdx.x;
  const int w = t >> 6, l = t & 63;
  const int wm = w >> 1, wn = w & 1;
  const size_t Kb = (size_t)K << 1;
  const int sR = t >> 2;
  const int sK = ((t ^ (t >> 2)) & 3) << 4;
  const int kq = (((l >> 4) ^ l) & 3) << 4;
  const int aRd = ((wm << 5) + (l & 15)) * 64 + kq;
  const int bRd = ((wn << 5) + (l & 15)) * 64 + kq;
  f32x4 acc[2][2] = {};
  for (int k0 = 0; k0 < K; k0 += 32){
    const size_t kb = (size_t)k0 << 1;
    load16((const u16*)(Ab + (size_t)(m0 + sR) * Kb + kb + sK), (u16*)(As + t * 16));
    load16((const u16*)(Bb + (size_t)(n0 + sR) * Kb + kb + sK), (u16*)(Bs + t * 16));
    __syncthreads();
    bf16x8 aF[2], bF[2];
#pragma unroll
    for (int mf = 0; mf < 2; ++mf) aF[mf] = *(const bf16x8*)(As + aRd + (mf << 10));
#pragma unroll
    for (int nf = 0; nf < 2; ++nf) bF[nf] = *(const bf16x8*)(Bs + bRd + (nf << 10));
#pragma unroll
    for (int mf = 0; mf < 2; ++mf)
#pragma unroll
      for (int nf = 0; nf < 2; ++nf)
        acc[mf][nf] = __builtin_amdgcn_mfma_f32_16x16x32_bf16(aF[mf], bF[nf], acc[mf][nf], 0, 0, 0);
    __syncthreads();
  }
#pragma unroll
  for (int mf = 0; mf < 2; ++mf){
#pragma unroll
    for (int nf = 0; nf < 2; ++nf){
      const int col = n0 + (wn << 5) + (nf << 4) + (l & 15);
#pragma unroll
      for (int q = 0; q < 4; ++q){
        const int row = m0 + (wm << 5) + (mf << 4) + ((l >> 4) << 2) + q;
        float v = acc[mf][nf][q];
        size_t gi = ((size_t)bz * M + row) * N + col;
        size_t g2 = (((size_t)bz * M + row) << 10) + col;
        if (EPI == 2){
          ((u16*)Cout)[gi] = f2bf(v);
        } else if (EPI == 3){
          ((u16*)Cout)[gi] = f2bf((row == col ? 2.0f : 0.0f) - v);
        } else if (EPI == 9){
          ((u16*)Cout)[gi] = f2bf(v - (row == col ? 1.0f : 0.0f));
        } else {  // EPI 11
          float p = v + (row == col ? 1.000002f : 0.0f);
          u16 ph = f2bf(p);
          ((u16*)Cout)[g2] = ph;
          ((u16*)Cout)[g2 + 512] = f2bf(p - bf2f(ph));
          const float beta = 0.8264463f;
          u16 x1 = f2bf((row == col ? 2.0f * beta : 0.0f) - beta * beta * p);
          ((u16*)aux)[gi] = x1;
          ((u16*)aux2)[g2] = x1;
          ((u16*)aux2)[g2 + 512] = x1;
        }
      }
    }
  }
}

// 256x256-tile bt-form bf16 MFMA gemm — ROUND-9 VERSION VERBATIM (replay-stable,
// 219.8 us @ MfmaUtil 57.3% = ~95% of the 8-wave structure's LDS-traffic ceiling:
// reads 192K + staging writes 64K per K-tile = 1024 cyc vs 621 MFMA cyc -> 60.6%).
// 512 threads (8 waves, 2Mx4N), BK=64, 2 LDS K-tile buffers (128 KiB). ONE
// barrier per K-tile; during tile t we stage ONLY tile t+1 into buffer (t+1)&1
// — never the buffer being read. vmcnt(0) at tile end waits on loads issued a
// full tile earlier. LDS XOR-swizzle byte^=((row&7)<<4) both-sides.
// [Round-10 lesson: 4-wave/256-acc (1 wave/SIMD) drops to 32.8% — no TLP.
//  Round-13/14 lesson: fusing f32->bf16 A-conversion in-kernel fails both ways:
//  shallow reg pipeline exposes ~900cyc HBM latency (34%), 2-tile-deep reg
//  pipeline spills (WRITE_SIZE 10x, 13%). Keep conv as separate pass.]
// EPI 0: f32 out = acc + aux[col] (bias) ; EPI 2: bf16 C = acc
template<int EPI>
__global__ __launch_bounds__(512, 2) void gemm256(const u16* __restrict__ A, const u16* __restrict__ B,
                                                  void* __restrict__ Cout, const float* __restrict__ aux,
                                                  int M, int N, int K){
  __shared__ __align__(16) char lds[131072];
  const int bz = blockIdx.z;
  const char* Ab = (const char*)(A + (size_t)bz * M * K);
  const char* Bb = (const char*)(B + (size_t)bz * N * K);
  const int NB = N >> 8;
  const int nwg = gridDim.x;
  const int bid = blockIdx.x;
  const int swzb = (bid & 7) * (nwg >> 3) + (bid >> 3);   // nwg % 8 == 0
  const int m0 = (swzb / NB) << 8;
  const int n0 = (swzb % NB) << 8;
  const int tid = threadIdx.x;
  const int w = tid >> 6, l = tid & 63;
  const int wm = w >> 2, wn = w & 3;
  const size_t Kb = (size_t)K << 1;
  const int NT = K >> 6;
  const int sRow = tid >> 3;
  const int sCol = ((tid & 7) << 4) ^ ((sRow & 7) << 4);
  const int sDst = tid << 4;
  const char* aS = Ab + (size_t)(m0 + sRow) * Kb + sCol;
  const char* bS = Bb + (size_t)(n0 + sRow) * Kb + sCol;
  const int lrow = (l & 15) << 7;
  const int kq0 = (((l >> 4) << 4)) ^ ((l & 7) << 4);
  const int aOff = (wm << 14) + lrow;
  const int bOff = 32768 + ((wn >> 1) << 14) + ((wn & 1) << 13) + lrow;

#define STAGE_H(isB, h, tt) { \
    const int _lo = (((tt) & 1) << 16) + ((isB) << 15) + ((h) << 14); \
    const char* _s = ((isB) ? bS : aS) + ((size_t)((h) << 7)) * Kb + ((size_t)(tt) << 7); \
    load16((const u16*)_s, (u16*)(lds + _lo + sDst)); \
    load16((const u16*)(_s + (Kb << 6)), (u16*)(lds + _lo + 8192 + sDst)); }

#define RD_A(bufb, UQ) \
  _Pragma("unroll") for (int i2 = 0; i2 < 4; ++i2){ \
    aF[i2][0] = *(const bf16x8*)(lds + (bufb) + aOff + ((UQ) << 13) + (i2 << 11) + kq0); \
    aF[i2][1] = *(const bf16x8*)(lds + (bufb) + aOff + ((UQ) << 13) + (i2 << 11) + (kq0 ^ 64)); }

#define RD_B(bufb, VQ) \
  _Pragma("unroll") for (int j2 = 0; j2 < 2; ++j2){ \
    bF[VQ][j2][0] = *(const bf16x8*)(lds + (bufb) + bOff + ((VQ) << 12) + (j2 << 11) + kq0); \
    bF[VQ][j2][1] = *(const bf16x8*)(lds + (bufb) + bOff + ((VQ) << 12) + (j2 << 11) + (kq0 ^ 64)); }

#define MFMA16(UQ, VQ) \
    _Pragma("unroll") for (int i2 = 0; i2 < 4; ++i2) \
      _Pragma("unroll") for (int j2 = 0; j2 < 2; ++j2){ \
        acc[(UQ)*4+i2][(VQ)*2+j2] = __builtin_amdgcn_mfma_f32_16x16x32_bf16(aF[i2][0], bF[VQ][j2][0], acc[(UQ)*4+i2][(VQ)*2+j2], 0, 0, 0); \
        acc[(UQ)*4+i2][(VQ)*2+j2] = __builtin_amdgcn_mfma_f32_16x16x32_bf16(aF[i2][1], bF[VQ][j2][1], acc[(UQ)*4+i2][(VQ)*2+j2], 0, 0, 0); }

#define BAR asm volatile("s_barrier" ::: "memory");
#define VM0 asm volatile("s_waitcnt vmcnt(0)" ::: "memory");

  bf16x8 aF[4][2], bF[2][2][2];
  f32x4 acc[8][4] = {};

  // prologue: stage tile 0 fully into buf 0
  STAGE_H(0,0,0) STAGE_H(1,0,0) STAGE_H(0,1,0) STAGE_H(1,1,0)
  VM0 BAR

  // one barrier per K-tile; stages target only the non-read buffer
#define KTILE(t, bufb) { \
    RD_A(bufb, 0) RD_B(bufb, 0) \
    if ((t) + 1 < NT) { STAGE_H(0,0,(t)+1) STAGE_H(1,0,(t)+1) } \
    MFMA16(0,0) \
    RD_B(bufb, 1) \
    if ((t) + 1 < NT) { STAGE_H(0,1,(t)+1) STAGE_H(1,1,(t)+1) } \
    MFMA16(0,1) \
    RD_A(bufb, 1) \
    MFMA16(1,1) \
    MFMA16(1,0) \
    __builtin_amdgcn_sched_barrier(0); \
    VM0 BAR }

#pragma unroll 1
  for (int tp = 0; tp < NT; tp += 2){
    KTILE(tp, 0)
    KTILE(tp+1, 65536)
  }
#undef KTILE

#pragma unroll
  for (int mf = 0; mf < 8; ++mf){
#pragma unroll
    for (int nf = 0; nf < 4; ++nf){
      const int col = n0 + (wn << 6) + (nf << 4) + (l & 15);
#pragma unroll
      for (int q = 0; q < 4; ++q){
        const int row = m0 + (wm << 7) + (mf << 4) + ((l >> 4) << 2) + q;
        float v = acc[mf][nf][q];
        if (EPI == 0){
          ((float*)Cout)[(size_t)row * N + col] = v + aux[col];
        } else {
          ((u16*)Cout)[((size_t)bz * M + row) * N + col] = f2bf(v);
        }
      }
    }
  }
#undef STAGE_H
#undef RD_A
#undef RD_B
#undef MFMA16
#undef BAR
#undef VM0
}

extern "C" void kernel_launch(void* const* d_in, const int* in_sizes, int n_in,
                              void* d_out, int out_size, void* d_ws, size_t ws_size,
                              hipStream_t stream){
  const float* W    = (const float*)d_in[0];
  const float* bias = (const float*)d_in[1];
  const float* x    = (const float*)d_in[2];
  const float* R    = (const float*)d_in[3];
  (void)in_sizes; (void)n_in; (void)out_size; (void)ws_size;

  char* ws = (char*)d_ws;
  const size_t MiB = (size_t)1 << 20;
  u16*   Sbf  = (u16*)(ws + 0 * MiB);    // 4 MiB ; reused as G
  u16*   Dbf  = (u16*)(ws + 4 * MiB);    // 4 MiB
  u16*   X1   = (u16*)(ws + 16 * MiB);   // 4 MiB
  u16*   Ybf  = (u16*)(ws + 20 * MiB);   // 4 MiB
  u16*   X2   = (u16*)(ws + 24 * MiB);   // 4 MiB
  u16*   Phl  = (u16*)(ws + 28 * MiB);   // 8 MiB  [Ph | Pl] width-1024
  u16*   X1d  = (u16*)(ws + 44 * MiB);   // 8 MiB  [X1 | X1] width-1024
  u16*   G    = Sbf;
  u16*   Wt   = (u16*)(ws + 8 * MiB);    // 32 MiB [8,40) — NS temps there dead by then
  u16*   filt = (u16*)(ws + 64 * MiB);   // 32 MiB [64,96)
  u16*   xbf  = (u16*)(ws + 0 * MiB);    // 64 MiB [0,64) — everything there dead by then

  const dim3 gNS(8, 8, 8);   // 512 blocks: 64x64 tiles, 2 blocks/CU (gemm_ns)

  // Phase 1: S (bf16) and D = (c+1)(cI - S)
  build_s<<<8192, 256, 0, stream>>>(R, Sbf, Dbf);
  // Phase 2: P = c^2 I + S S^T ; fused epilogue emits Phl=[Ph|Pl], X1, X1d
  gemm_ns<11><<<gNS, 256, 0, stream>>>(Sbf, Sbf, Phl, X1, X1d, 512, 512, 512);
  // Phase 3: Y = 2I - (Ph+Pl) X1   (one K=1024 gemm, full-precision P)
  gemm_ns<3><<<gNS, 256, 0, stream>>>(Phl, X1d, Ybf, nullptr, nullptr, 512, 512, 1024);
  // Phase 4: X2 = X1 Y
  gemm_ns<2><<<gNS, 256, 0, stream>>>(X1, Ybf, X2, nullptr, nullptr, 512, 512, 512);
  // Phase 5: G = Q = D X2 - I
  gemm_ns<9><<<gNS, 256, 0, stream>>>(Dbf, X2, G, nullptr, nullptr, 512, 512, 512);
  // Phase 6: filt = G @ Wb (bf16)
  transpose_w<<<dim3(128, 16, 8), 256, 0, stream>>>(W, Wt);
  gemm256<2><<<dim3(32, 1, 8), 512, 0, stream>>>(G, Wt, (void*)filt, nullptr, 512, 4096, 512);
  // Phase 7: x -> bf16 (must run after NS temps/Wt are dead — xbf aliases [0,64))
  conv_bf16<<<16384, 256, 0, stream>>>(x, xbf);
  // Phase 8: out = x @ filt^T + bias
  gemm256<0><<<dim3(512, 1, 1), 512, 0, stream>>>(xbf, filt, d_out, bias, 8192, 4096, 4096);
}

// Round 18
// 345.977 us; speedup vs baseline: 2.6473x; 1.0033x over previous
//
#include <hip/hip_runtime.h>

typedef unsigned short u16;
typedef __attribute__((ext_vector_type(8))) short bf16x8;
typedef __attribute__((ext_vector_type(4))) float f32x4;
typedef __attribute__((ext_vector_type(8))) unsigned short u16x8;
typedef __attribute__((ext_vector_type(4))) unsigned short u16x4;

__device__ __forceinline__ u16 f2bf(float f){
  unsigned int u = __builtin_bit_cast(unsigned int, f);
  u += 0x7FFFu + ((u >> 16) & 1u);
  return (u16)(u >> 16);
}
__device__ __forceinline__ float bf2f(u16 h){
  unsigned int u = ((unsigned int)h) << 16;
  return __builtin_bit_cast(float, u);
}

__device__ __forceinline__ void load16(const u16* g, u16* s){
  __builtin_amdgcn_global_load_lds((const __attribute__((address_space(1))) unsigned int*)g,
                                   (__attribute__((address_space(3))) unsigned int*)s,
                                   16, 0, 0);
}

// Fused preamble (build_s + W-transpose; independent, disjoint outputs).
// All 16384 blocks: one 32x32 W-transpose tile -> Wt[b][i][j] = bf16(W[b*512+j][i]).
// Blocks < 8192 additionally: one 256-elem chunk of
//   S = 0.5(A-A^T): Sbf = bf16(S); Dbf = bf16((c+1)(cI - S)), c = 1.000001.
// [R16/R17 lesson: the identical absmax=17.109 in both rounds was Wt@[8,40)
//  being clobbered by NS temps when the transpose moved to the front — NOT a
//  cooperative-launch failure. Fix = layout: Wt now at [64,96), disjoint from
//  NS temps [0,36) for its whole lifetime.]
__global__ __launch_bounds__(256) void prep_sw(const float* __restrict__ R, const float* __restrict__ W,
                                               u16* __restrict__ Sbf, u16* __restrict__ Dbf,
                                               u16* __restrict__ Wt){
  const int blk = blockIdx.x;
  const int t = threadIdx.x;
  if (blk < 8192){
    int idx = blk * 256 + t;
    int b = idx >> 18;
    int i = (idx >> 9) & 511;
    int j = idx & 511;
    float a  = R[idx];
    float at = R[(b << 18) + (j << 9) + i];
    float s = 0.5f * (a - at);
    Sbf[idx] = f2bf(s);
    Dbf[idx] = f2bf((i == j ? 2.000003f : 0.0f) - 2.000001f * s);
  }
  __shared__ float tile[32][33];
  const int fx = blk & 127, fy = (blk >> 7) & 15, fz = blk >> 11;
  const int i0 = fx << 5, j0 = fy << 5;
  const int r = t >> 3, c = (t & 7) << 2;
  float4 v = *(const float4*)&W[(size_t)((fz << 9) + j0 + r) * 4096 + i0 + c];
  tile[r][c+0] = v.x; tile[r][c+1] = v.y; tile[r][c+2] = v.z; tile[r][c+3] = v.w;
  __syncthreads();
  u16x4 o = { f2bf(tile[c+0][r]), f2bf(tile[c+1][r]), f2bf(tile[c+2][r]), f2bf(tile[c+3][r]) };
  *(u16x4*)&Wt[((size_t)fz << 21) + (size_t)(i0 + r) * 512 + j0 + c] = o;
}

// vectorized f32 -> bf16 (8 elems / thread, exact multiple)
__global__ __launch_bounds__(256) void conv_bf16(const float* __restrict__ src, u16* __restrict__ dst){
  size_t i = (size_t)blockIdx.x * 256 + threadIdx.x;
  const float4* s = (const float4*)src + i * 2;
  float4 v0 = s[0], v1 = s[1];
  u16x8 o = { f2bf(v0.x), f2bf(v0.y), f2bf(v0.z), f2bf(v0.w),
              f2bf(v1.x), f2bf(v1.y), f2bf(v1.z), f2bf(v1.w) };
  *(u16x8*)(dst + i * 8) = o;
}

// 64x64-tile bt-form bf16 MFMA gemm for the small NS steps: grid (N/64, M/64, 8)
// = 512 blocks (2 blocks/CU). 4 waves (2Mx2N), each 32x32 (2x2 16x16x32 frags).
// Single-buffered LDS, __syncthreads staging (deterministic class), 4-slot XOR
// swizzle: LDS[r][slot] = G[r][slot ^ (r&3)], read slot ((l>>4)^l)&3.
// EPI 2:  bf16 C = acc
// EPI 3:  bf16 C = 2*diag - acc
// EPI 9:  bf16 C = acc - diag
// EPI 11: p = acc + c^2*diag (f32): Cout(width1024)=[bf16(p)|bf16(p-ph)];
//         x1 = bf16(2b*diag - b^2*p) -> aux (width 512) and aux2 (width 1024, dup)
template<int EPI>
__global__ __launch_bounds__(256) void gemm_ns(const u16* __restrict__ A, const u16* __restrict__ B,
                                               void* __restrict__ Cout, void* __restrict__ aux,
                                               void* __restrict__ aux2,
                                               int M, int N, int K){
  const int bz = blockIdx.z;
  const char* Ab = (const char*)(A + (size_t)bz * M * K);
  const char* Bb = (const char*)(B + (size_t)bz * N * K);
  const int m0 = blockIdx.y << 6, n0 = blockIdx.x << 6;
  __shared__ __align__(16) char As[4096];
  __shared__ __align__(16) char Bs[4096];
  const int t = threadIdx.x;
  const int w = t >> 6, l = t & 63;
  const int wm = w >> 1, wn = w & 1;
  const size_t Kb = (size_t)K << 1;
  const int sR = t >> 2;
  const int sK = ((t ^ (t >> 2)) & 3) << 4;
  const int kq = (((l >> 4) ^ l) & 3) << 4;
  const int aRd = ((wm << 5) + (l & 15)) * 64 + kq;
  const int bRd = ((wn << 5) + (l & 15)) * 64 + kq;
  f32x4 acc[2][2] = {};
  for (int k0 = 0; k0 < K; k0 += 32){
    const size_t kb = (size_t)k0 << 1;
    load16((const u16*)(Ab + (size_t)(m0 + sR) * Kb + kb + sK), (u16*)(As + t * 16));
    load16((const u16*)(Bb + (size_t)(n0 + sR) * Kb + kb + sK), (u16*)(Bs + t * 16));
    __syncthreads();
    bf16x8 aF[2], bF[2];
#pragma unroll
    for (int mf = 0; mf < 2; ++mf) aF[mf] = *(const bf16x8*)(As + aRd + (mf << 10));
#pragma unroll
    for (int nf = 0; nf < 2; ++nf) bF[nf] = *(const bf16x8*)(Bs + bRd + (nf << 10));
#pragma unroll
    for (int mf = 0; mf < 2; ++mf)
#pragma unroll
      for (int nf = 0; nf < 2; ++nf)
        acc[mf][nf] = __builtin_amdgcn_mfma_f32_16x16x32_bf16(aF[mf], bF[nf], acc[mf][nf], 0, 0, 0);
    __syncthreads();
  }
#pragma unroll
  for (int mf = 0; mf < 2; ++mf){
#pragma unroll
    for (int nf = 0; nf < 2; ++nf){
      const int col = n0 + (wn << 5) + (nf << 4) + (l & 15);
#pragma unroll
      for (int q = 0; q < 4; ++q){
        const int row = m0 + (wm << 5) + (mf << 4) + ((l >> 4) << 2) + q;
        float v = acc[mf][nf][q];
        size_t gi = ((size_t)bz * M + row) * N + col;
        size_t g2 = (((size_t)bz * M + row) << 10) + col;
        if (EPI == 2){
          ((u16*)Cout)[gi] = f2bf(v);
        } else if (EPI == 3){
          ((u16*)Cout)[gi] = f2bf((row == col ? 2.0f : 0.0f) - v);
        } else if (EPI == 9){
          ((u16*)Cout)[gi] = f2bf(v - (row == col ? 1.0f : 0.0f));
        } else {  // EPI 11
          float p = v + (row == col ? 1.000002f : 0.0f);
          u16 ph = f2bf(p);
          ((u16*)Cout)[g2] = ph;
          ((u16*)Cout)[g2 + 512] = f2bf(p - bf2f(ph));
          const float beta = 0.8264463f;
          u16 x1 = f2bf((row == col ? 2.0f * beta : 0.0f) - beta * beta * p);
          ((u16*)aux)[gi] = x1;
          ((u16*)aux2)[g2] = x1;
          ((u16*)aux2)[g2 + 512] = x1;
        }
      }
    }
  }
}

// 256x256-tile bt-form bf16 MFMA gemm — ROUND-9 VERSION VERBATIM (replay-stable,
// 219.8 us @ MfmaUtil 57.3% = ~95% of the 8-wave structure's LDS-traffic ceiling:
// reads 192K + staging writes 64K per K-tile = 1024 cyc vs 621 MFMA cyc -> 60.6%).
// 512 threads (8 waves, 2Mx4N), BK=64, 2 LDS K-tile buffers (128 KiB). ONE
// barrier per K-tile; during tile t we stage ONLY tile t+1 into buffer (t+1)&1
// — never the buffer being read. vmcnt(0) at tile end waits on loads issued a
// full tile earlier. LDS XOR-swizzle byte^=((row&7)<<4) both-sides.
// [R10: 1 wave/SIMD -> 32.8%, no TLP. R13/14: in-kernel f32->bf16 A-fusion
//  fails both shallow (HBM latency, 34%) and deep (spill, 13%).]
// EPI 0: f32 out = acc + aux[col] (bias) ; EPI 2: bf16 C = acc
template<int EPI>
__global__ __launch_bounds__(512, 2) void gemm256(const u16* __restrict__ A, const u16* __restrict__ B,
                                                  void* __restrict__ Cout, const float* __restrict__ aux,
                                                  int M, int N, int K){
  __shared__ __align__(16) char lds[131072];
  const int bz = blockIdx.z;
  const char* Ab = (const char*)(A + (size_t)bz * M * K);
  const char* Bb = (const char*)(B + (size_t)bz * N * K);
  const int NB = N >> 8;
  const int nwg = gridDim.x;
  const int bid = blockIdx.x;
  const int swzb = (bid & 7) * (nwg >> 3) + (bid >> 3);   // nwg % 8 == 0
  const int m0 = (swzb / NB) << 8;
  const int n0 = (swzb % NB) << 8;
  const int tid = threadIdx.x;
  const int w = tid >> 6, l = tid & 63;
  const int wm = w >> 2, wn = w & 3;
  const size_t Kb = (size_t)K << 1;
  const int NT = K >> 6;
  const int sRow = tid >> 3;
  const int sCol = ((tid & 7) << 4) ^ ((sRow & 7) << 4);
  const int sDst = tid << 4;
  const char* aS = Ab + (size_t)(m0 + sRow) * Kb + sCol;
  const char* bS = Bb + (size_t)(n0 + sRow) * Kb + sCol;
  const int lrow = (l & 15) << 7;
  const int kq0 = (((l >> 4) << 4)) ^ ((l & 7) << 4);
  const int aOff = (wm << 14) + lrow;
  const int bOff = 32768 + ((wn >> 1) << 14) + ((wn & 1) << 13) + lrow;

#define STAGE_H(isB, h, tt) { \
    const int _lo = (((tt) & 1) << 16) + ((isB) << 15) + ((h) << 14); \
    const char* _s = ((isB) ? bS : aS) + ((size_t)((h) << 7)) * Kb + ((size_t)(tt) << 7); \
    load16((const u16*)_s, (u16*)(lds + _lo + sDst)); \
    load16((const u16*)(_s + (Kb << 6)), (u16*)(lds + _lo + 8192 + sDst)); }

#define RD_A(bufb, UQ) \
  _Pragma("unroll") for (int i2 = 0; i2 < 4; ++i2){ \
    aF[i2][0] = *(const bf16x8*)(lds + (bufb) + aOff + ((UQ) << 13) + (i2 << 11) + kq0); \
    aF[i2][1] = *(const bf16x8*)(lds + (bufb) + aOff + ((UQ) << 13) + (i2 << 11) + (kq0 ^ 64)); }

#define RD_B(bufb, VQ) \
  _Pragma("unroll") for (int j2 = 0; j2 < 2; ++j2){ \
    bF[VQ][j2][0] = *(const bf16x8*)(lds + (bufb) + bOff + ((VQ) << 12) + (j2 << 11) + kq0); \
    bF[VQ][j2][1] = *(const bf16x8*)(lds + (bufb) + bOff + ((VQ) << 12) + (j2 << 11) + (kq0 ^ 64)); }

#define MFMA16(UQ, VQ) \
    _Pragma("unroll") for (int i2 = 0; i2 < 4; ++i2) \
      _Pragma("unroll") for (int j2 = 0; j2 < 2; ++j2){ \
        acc[(UQ)*4+i2][(VQ)*2+j2] = __builtin_amdgcn_mfma_f32_16x16x32_bf16(aF[i2][0], bF[VQ][j2][0], acc[(UQ)*4+i2][(VQ)*2+j2], 0, 0, 0); \
        acc[(UQ)*4+i2][(VQ)*2+j2] = __builtin_amdgcn_mfma_f32_16x16x32_bf16(aF[i2][1], bF[VQ][j2][1], acc[(UQ)*4+i2][(VQ)*2+j2], 0, 0, 0); }

#define BAR asm volatile("s_barrier" ::: "memory");
#define VM0 asm volatile("s_waitcnt vmcnt(0)" ::: "memory");

  bf16x8 aF[4][2], bF[2][2][2];
  f32x4 acc[8][4] = {};

  // prologue: stage tile 0 fully into buf 0
  STAGE_H(0,0,0) STAGE_H(1,0,0) STAGE_H(0,1,0) STAGE_H(1,1,0)
  VM0 BAR

  // one barrier per K-tile; stages target only the non-read buffer
#define KTILE(t, bufb) { \
    RD_A(bufb, 0) RD_B(bufb, 0) \
    if ((t) + 1 < NT) { STAGE_H(0,0,(t)+1) STAGE_H(1,0,(t)+1) } \
    MFMA16(0,0) \
    RD_B(bufb, 1) \
    if ((t) + 1 < NT) { STAGE_H(0,1,(t)+1) STAGE_H(1,1,(t)+1) } \
    MFMA16(0,1) \
    RD_A(bufb, 1) \
    MFMA16(1,1) \
    MFMA16(1,0) \
    __builtin_amdgcn_sched_barrier(0); \
    VM0 BAR }

#pragma unroll 1
  for (int tp = 0; tp < NT; tp += 2){
    KTILE(tp, 0)
    KTILE(tp+1, 65536)
  }
#undef KTILE

#pragma unroll
  for (int mf = 0; mf < 8; ++mf){
#pragma unroll
    for (int nf = 0; nf < 4; ++nf){
      const int col = n0 + (wn << 6) + (nf << 4) + (l & 15);
#pragma unroll
      for (int q = 0; q < 4; ++q){
        const int row = m0 + (wm << 7) + (mf << 4) + ((l >> 4) << 2) + q;
        float v = acc[mf][nf][q];
        if (EPI == 0){
          ((float*)Cout)[(size_t)row * N + col] = v + aux[col];
        } else {
          ((u16*)Cout)[((size_t)bz * M + row) * N + col] = f2bf(v);
        }
      }
    }
  }
#undef STAGE_H
#undef RD_A
#undef RD_B
#undef MFMA16
#undef BAR
#undef VM0
}

extern "C" void kernel_launch(void* const* d_in, const int* in_sizes, int n_in,
                              void* d_out, int out_size, void* d_ws, size_t ws_size,
                              hipStream_t stream){
  const float* W    = (const float*)d_in[0];
  const float* bias = (const float*)d_in[1];
  const float* x    = (const float*)d_in[2];
  const float* R    = (const float*)d_in[3];
  (void)in_sizes; (void)n_in; (void)out_size; (void)ws_size;

  char* ws = (char*)d_ws;
  const size_t MiB = (size_t)1 << 20;
  // Lifetime-audited layout (max extent 100 MiB = round-1-proven budget):
  //   phase 1  : writes Sbf[0,4) Dbf[4,8) Wt[64,96)
  //   phase 2-5: NS temps all within [0,36); Wt untouched
  //   phase 6  : reads G[0,4)+Wt[64,96), writes filt[4,36) (NS temps dead)
  //   phase 7  : writes xbf[36,100) (clobbers only dead X1d/Wt)
  //   phase 8  : reads xbf[36,100) + filt[4,36)
  u16*   Sbf  = (u16*)(ws + 0 * MiB);    // 4 MiB ; reused as G
  u16*   Dbf  = (u16*)(ws + 4 * MiB);    // 4 MiB
  u16*   X1   = (u16*)(ws + 8 * MiB);    // 4 MiB
  u16*   Ybf  = (u16*)(ws + 12 * MiB);   // 4 MiB
  u16*   X2   = (u16*)(ws + 16 * MiB);   // 4 MiB
  u16*   Phl  = (u16*)(ws + 20 * MiB);   // 8 MiB  [Ph | Pl] width-1024
  u16*   X1d  = (u16*)(ws + 28 * MiB);   // 8 MiB  [X1 | X1] width-1024
  u16*   G    = Sbf;
  u16*   filt = (u16*)(ws + 4 * MiB);    // 32 MiB [4,36) — written phase 6, NS temps dead
  u16*   Wt   = (u16*)(ws + 64 * MiB);   // 32 MiB [64,96) — disjoint from NS temps for its lifetime
  u16*   xbf  = (u16*)(ws + 36 * MiB);   // 64 MiB [36,100) — written phase 7 (X1d/Wt dead)

  const dim3 gNS(8, 8, 8);   // 512 blocks: 64x64 tiles, 2 blocks/CU (gemm_ns)

  // Phase 1: fused build_s + W-transpose (one dispatch)
  prep_sw<<<16384, 256, 0, stream>>>(R, W, Sbf, Dbf, Wt);
  // Phase 2: P = c^2 I + S S^T ; fused epilogue emits Phl=[Ph|Pl], X1, X1d
  gemm_ns<11><<<gNS, 256, 0, stream>>>(Sbf, Sbf, Phl, X1, X1d, 512, 512, 512);
  // Phase 3: Y = 2I - (Ph+Pl) X1   (one K=1024 gemm, full-precision P)
  gemm_ns<3><<<gNS, 256, 0, stream>>>(Phl, X1d, Ybf, nullptr, nullptr, 512, 512, 1024);
  // Phase 4: X2 = X1 Y
  gemm_ns<2><<<gNS, 256, 0, stream>>>(X1, Ybf, X2, nullptr, nullptr, 512, 512, 512);
  // Phase 5: G = Q = D X2 - I
  gemm_ns<9><<<gNS, 256, 0, stream>>>(Dbf, X2, G, nullptr, nullptr, 512, 512, 512);
  // Phase 6: filt = G @ Wb (bf16)
  gemm256<2><<<dim3(32, 1, 8), 512, 0, stream>>>(G, Wt, (void*)filt, nullptr, 512, 4096, 512);
  // Phase 7: x -> bf16
  conv_bf16<<<16384, 256, 0, stream>>>(x, xbf);
  // Phase 8: out = x @ filt^T + bias
  gemm256<0><<<dim3(512, 1, 1), 512, 0, stream>>>(xbf, filt, d_out, bias, 8192, 4096, 4096);
}